// Round 5
// baseline (212.225 us; speedup 1.0000x reference)
//
#include <hip/hip_runtime.h>
#include <hip/hip_fp16.h>
#include <math.h>

#define N_GENES 20000
#define UNITS   10000
#define DEG     32
#define BATCH   128
#define UPB     16                  // units per block
#define NBLOCKS (UNITS / UPB)       // 625  (== N_GENES/32 gene slabs)
#define MAGIC_ARRIVE 0xC0FFEE01u
#define MAGIC_GO     0xC0FFEE02u

// One fused kernel: phase 1 transposes a 32-gene slab (fp32 [B,G] -> fp16 [G,B]),
// software grid barrier, phase 2 gathers 16 units over all 128 batches.
// Co-residency: 625 blocks, 4 waves + 14.4 KB LDS each -> min(8,11) blocks/CU
// possible, 2.44 needed, so all blocks are resident; barrier cannot deadlock.
// Barrier flags live in d_ws (re-poisoned 0xAA every launch; any value
// != MAGIC_ARRIVE is a safe initial state).
__global__ __launch_bounds__(256) void ppi_fused_kernel(
    const float* __restrict__ feature,
    const int*   __restrict__ ppi,
    const float* __restrict__ kernelw,
    const float* __restrict__ bias,
    float*       __restrict__ out,
    __half*      __restrict__ featT,     // ws: [N_GENES][BATCH] fp16, 5.12 MB
    unsigned*    __restrict__ flags,     // ws: [NBLOCKS]
    unsigned*    __restrict__ go)        // ws: single word
{
    __shared__ float tile[32][33];       // 4.2 KB
    __shared__ int   idx[UPB * DEG];     // 2 KB
    __shared__ float res[UPB][BATCH];    // 8 KB

    const int tid = threadIdx.x;
    const int bid = blockIdx.x;
    const int u0  = bid * UPB;

    // stage this block's 512 ppi indices (overlaps with transpose loads)
    {
        const int* src = ppi + (size_t)u0 * DEG;
        idx[tid]       = src[tid];
        idx[tid + 256] = src[tid + 256];
    }

    // ---- phase 1: transpose+abs genes [32*bid, 32*bid+32) ----
    const int g0 = bid * 32;
    const int tx = tid & 31;
    const int ty = tid >> 5;             // 0..7
    for (int b0 = 0; b0 < BATCH; b0 += 32) {
#pragma unroll
        for (int i = 0; i < 32; i += 8)
            tile[ty + i][tx] = fabsf(feature[(size_t)(b0 + ty + i) * N_GENES + g0 + tx]);
        __syncthreads();
#pragma unroll
        for (int i = 0; i < 32; i += 8)
            featT[(size_t)(g0 + ty + i) * BATCH + b0 + tx] = __float2half(tile[tx][ty + i]);
        __syncthreads();                 // tile reuse
    }

    // ---- grid barrier: arrive flags + single go word ----
    if (tid == 0) {
        __threadfence();                 // featT writes visible device-wide
        __hip_atomic_store(&flags[bid], MAGIC_ARRIVE,
                           __ATOMIC_RELEASE, __HIP_MEMORY_SCOPE_AGENT);
    }
    if (bid == 0) {
        for (;;) {
            int mine = 1;
            for (int i = tid; i < NBLOCKS; i += 256)
                mine &= (__hip_atomic_load(&flags[i], __ATOMIC_ACQUIRE,
                                           __HIP_MEMORY_SCOPE_AGENT) == MAGIC_ARRIVE);
            if (__syncthreads_and(mine)) break;
            __builtin_amdgcn_s_sleep(8);
        }
        if (tid == 0)
            __hip_atomic_store(go, MAGIC_GO,
                               __ATOMIC_RELEASE, __HIP_MEMORY_SCOPE_AGENT);
    } else {
        if (tid == 0) {
            while (__hip_atomic_load(go, __ATOMIC_ACQUIRE,
                                     __HIP_MEMORY_SCOPE_AGENT) != MAGIC_GO)
                __builtin_amdgcn_s_sleep(8);
        }
    }
    __syncthreads();
    __threadfence();                     // invalidate stale lines before gather

    // ---- phase 2: gather. wave w: units w*4..w*4+3; quarter-wave q: d parity;
    //      lane c: batches 8c..8c+7 via one dwordx4 (full 256-B row per wave) ----
    const int lane = tid & 63;
    const int w    = tid >> 6;
    const int q    = lane >> 4;
    const int c    = lane & 15;

#pragma unroll 2
    for (int uu = 0; uu < 4; ++uu) {
        const int ul = w * 4 + uu;
        float acc[8] = {0.f,0.f,0.f,0.f,0.f,0.f,0.f,0.f};
#pragma unroll
        for (int it = 0; it < 8; ++it) {
            const int g = idx[ul * DEG + it * 4 + q];
            const float4 raw = *(const float4*)(featT + (size_t)g * BATCH + c * 8);
            const __half2* h2 = (const __half2*)&raw;
#pragma unroll
            for (int p = 0; p < 4; ++p) {
                const float2 f = __half22float2(h2[p]);
                acc[2 * p]     += f.x;
                acc[2 * p + 1] += f.y;
            }
        }
#pragma unroll
        for (int j = 0; j < 8; ++j) {
            float v = acc[j];
            v += __shfl_xor(v, 16, 64);
            v += __shfl_xor(v, 32, 64);
            acc[j] = v;
        }
        if (q == 0) {
            const int u = u0 + ul;
            const float kk = kernelw[u];
            const float bb = bias[u];
#pragma unroll
            for (int j = 0; j < 8; ++j) {
                const float h = acc[j] * kk + bb;
                res[ul][c * 8 + j] = 1.f - 2.f / (__expf(2.f * h) + 1.f);
            }
        }
    }
    __syncthreads();

    // write out[b][u0..u0+15]: 2 threads per batch row -> full 64-B lines
    const int b    = tid >> 1;
    const int half = tid & 1;
    float v[8];
#pragma unroll
    for (int j = 0; j < 8; ++j) v[j] = res[half * 8 + j][b];
    float4* o = (float4*)(out + (size_t)b * UNITS + u0 + half * 8);
    o[0] = make_float4(v[0], v[1], v[2], v[3]);
    o[1] = make_float4(v[4], v[5], v[6], v[7]);
}

extern "C" void kernel_launch(void* const* d_in, const int* in_sizes, int n_in,
                              void* d_out, int out_size, void* d_ws, size_t ws_size,
                              hipStream_t stream) {
    const float* feature = (const float*)d_in[0];
    const int*   ppi     = (const int*)d_in[1];
    const float* kernelw = (const float*)d_in[2];
    const float* bias    = (const float*)d_in[3];
    float* out = (float*)d_out;

    char* ws = (char*)d_ws;
    __half*   featT = (__half*)ws;                         // 5.12 MB
    unsigned* flags = (unsigned*)(ws + (6u << 20));        // 625 words @ 6 MB
    unsigned* go    = (unsigned*)(ws + (6u << 20) + 4096); // 1 word

    ppi_fused_kernel<<<NBLOCKS, 256, 0, stream>>>(
        feature, ppi, kernelw, bias, out, featT, flags, go);
}

// Round 6
// 88.934 us; speedup vs baseline: 2.3863x; 2.3863x over previous
//
#include <hip/hip_runtime.h>
#include <hip/hip_fp16.h>
#include <math.h>

#define N_GENES 20000
#define UNITS   10000
#define DEG     32
#define BATCH   128
#define UPB     8     // units per gather block

// Kernel 1: featT[p][g][b'] = (half)|feature[b][g]|, p = b>>6, b' = b&63.
// Two 2.56 MB batch-planes; each gather launch touches exactly one plane,
// which fits a 4 MB per-XCD L2 with room to spare.
__global__ __launch_bounds__(256) void transpose_abs_f16_kernel(
    const float* __restrict__ in, __half* __restrict__ out)
{
    __shared__ float tile[32][33];
    const int g0 = blockIdx.x * 32;
    const int b0 = blockIdx.y * 32;
    const int tx = threadIdx.x;   // 0..31
    const int ty = threadIdx.y;   // 0..7
#pragma unroll
    for (int i = 0; i < 32; i += 8)
        tile[ty + i][tx] = fabsf(in[(size_t)(b0 + ty + i) * N_GENES + (g0 + tx)]);
    __syncthreads();
    const int b  = b0 + tx;
    const size_t plane = (size_t)(b >> 6) * N_GENES * 64;
    const int bp = b & 63;
#pragma unroll
    for (int i = 0; i < 32; i += 8)
        out[plane + (size_t)(g0 + ty + i) * 64 + bp] = __float2half(tile[tx][ty + i]);
}

// Kernel 2 (launched twice, once per batch-plane): 1250 blocks x 4 waves,
// 8 units/block, 2 units/wave. Lane: dh = lane>>5 is d-parity, c = lane&31
// covers batches 2c,2c+1 (one half2 = 4 B; half-wave = full 128-B gene row).
// Working set per launch = one 2.56 MB plane -> L2-resident device-wide.
// Output stores are nontemporal so 2.56 MB of `out` doesn't evict the plane.
__global__ __launch_bounds__(256) void gather_half_kernel(
    const __half2* __restrict__ plane,   // [N_GENES][32] half2
    const int*   __restrict__ ppi,
    const float* __restrict__ kernelw,
    const float* __restrict__ bias,
    float*       __restrict__ outh)      // out + b0*UNITS
{
    __shared__ int idx[UPB * DEG];       // 256 ints
    const int tid = threadIdx.x;
    const int u0  = blockIdx.x * UPB;

    idx[tid] = ppi[(size_t)u0 * DEG + tid];
    __syncthreads();

    const int lane = tid & 63;
    const int w    = tid >> 6;           // wave 0..3
    const int dh   = lane >> 5;          // d parity
    const int c    = lane & 31;          // batches 2c, 2c+1
    const int ub   = w * 2;              // local unit base

    float2 acc0 = {0.f, 0.f}, acc1 = {0.f, 0.f};
#pragma unroll
    for (int it = 0; it < 16; ++it) {
        const int d  = it * 2 + dh;
        const int g0 = idx[ub * DEG + d];          // LDS broadcast
        const int g1 = idx[(ub + 1) * DEG + d];
        const float2 f0 = __half22float2(plane[(size_t)g0 * 32 + c]);
        const float2 f1 = __half22float2(plane[(size_t)g1 * 32 + c]);
        acc0.x += f0.x; acc0.y += f0.y;
        acc1.x += f1.x; acc1.y += f1.y;
    }
    // combine d-parity halves (lane <-> lane^32)
    acc0.x += __shfl_xor(acc0.x, 32, 64);
    acc0.y += __shfl_xor(acc0.y, 32, 64);
    acc1.x += __shfl_xor(acc1.x, 32, 64);
    acc1.y += __shfl_xor(acc1.y, 32, 64);

    if (dh == 0) {
        const int u  = u0 + ub;
        const float k0 = kernelw[u],     k1 = kernelw[u + 1];
        const float c0 = bias[u],        c1 = bias[u + 1];
        const float h00 = acc0.x * k0 + c0;   // batch 2c,   unit u
        const float h10 = acc1.x * k1 + c1;   // batch 2c,   unit u+1
        const float h01 = acc0.y * k0 + c0;   // batch 2c+1, unit u
        const float h11 = acc1.y * k1 + c1;   // batch 2c+1, unit u+1
        // tanh(h) = 1 - 2/(exp(2h)+1)
        const float r00 = 1.f - 2.f / (__expf(2.f * h00) + 1.f);
        const float r10 = 1.f - 2.f / (__expf(2.f * h10) + 1.f);
        const float r01 = 1.f - 2.f / (__expf(2.f * h01) + 1.f);
        const float r11 = 1.f - 2.f / (__expf(2.f * h11) + 1.f);

        const int b = c * 2;
        float2 v0 = make_float2(r00, r10);
        float2 v1 = make_float2(r01, r11);
        // nontemporal: keep the featT plane resident in L2
        __builtin_nontemporal_store(*(const double*)&v0,
            (double*)(outh + (size_t)b * UNITS + u));
        __builtin_nontemporal_store(*(const double*)&v1,
            (double*)(outh + (size_t)(b + 1) * UNITS + u));
    }
}

extern "C" void kernel_launch(void* const* d_in, const int* in_sizes, int n_in,
                              void* d_out, int out_size, void* d_ws, size_t ws_size,
                              hipStream_t stream) {
    const float* feature = (const float*)d_in[0];
    const int*   ppi     = (const int*)d_in[1];
    const float* kernelw = (const float*)d_in[2];
    const float* bias    = (const float*)d_in[3];
    float* out = (float*)d_out;
    __half* featT = (__half*)d_ws;       // [2][N_GENES][64] fp16, 5.12 MB

    dim3 g1(N_GENES / 32, BATCH / 32);
    dim3 b1(32, 8);
    transpose_abs_f16_kernel<<<g1, b1, 0, stream>>>(feature, featT);

    const __half2* plane0 = (const __half2*)featT;
    const __half2* plane1 = (const __half2*)(featT + (size_t)N_GENES * 64);
    gather_half_kernel<<<UNITS / UPB, 256, 0, stream>>>(
        plane0, ppi, kernelw, bias, out);
    gather_half_kernel<<<UNITS / UPB, 256, 0, stream>>>(
        plane1, ppi, kernelw, bias, out + (size_t)64 * UNITS);
}